// Round 7
// baseline (441.179 us; speedup 1.0000x reference)
//
#include <hip/hip_runtime.h>
#include <hip/hip_bf16.h>

#define NQ 65536
#define DIM 512
#define HID 256
#define NWAY 5
#define NKPTS 17

typedef short bf16x8 __attribute__((ext_vector_type(8)));
typedef float f32x4 __attribute__((ext_vector_type(4)));
typedef _Float16 half8 __attribute__((ext_vector_type(8)));

static __device__ __forceinline__ unsigned short f2bf(float f) {
    unsigned int x = __float_as_uint(f);
    unsigned int r = (x + 0x7fffu + ((x >> 16) & 1u)) >> 16;
    return (unsigned short)r;
}

// ============================================================================
// Fragment-ordered staging layouts (16B chunk per lane, frag = 1 dwordx4):
//  A (qb):  byte addr = mb*65536 + (it*4+mt)*1024 + (qg*16 + r)*16
//           lane l=(qg*16+r) holds A[mb*64 + mt*16 + r][it*32 + qg*8 .. +7]
//  B (wbT): byte addr = (it*8 + c64)*4096 + nt*1024 + (qg*16 + r)*16
//           lane holds B[c64*64 + nt*16 + r][it*32 + qg*8 .. +7]   (c64 = col>>6)
// ============================================================================

// ---------------- k_l1: support layer1 (coalesced) + [Wo1|Wc1] -> frag-ordered bf16 wbT --------
__global__ __launch_bounds__(256) void k_l1(const float* __restrict__ sf,
                                            const float* __restrict__ W1, const float* __restrict__ b1,
                                            const float* __restrict__ Wo1, const float* __restrict__ Wc1,
                                            float* __restrict__ ws_h1, unsigned short* __restrict__ wbT) {
    int bx = blockIdx.x, t = threadIdx.x;
    if (bx < 50) {
        __shared__ float s_sf[DIM];
        int s = bx >> 1, c = (bx & 1) * 256 + t;
        s_sf[t] = sf[s * DIM + t];
        s_sf[t + 256] = sf[s * DIM + 256 + t];
        __syncthreads();
        float acc = 0.0f;
        #pragma unroll 8
        for (int k = 0; k < DIM; k++) acc += W1[k * DIM + c] * s_sf[k];
        ws_h1[s * DIM + c] = fmaxf(acc + b1[c], 0.0f);
    } else {
        __shared__ unsigned short T[64][72];
        int tb = bx - 50;                    // 0..63
        const float* src = (tb < 32) ? Wo1 : Wc1;
        int cofs = (tb < 32) ? 0 : 256;
        int tt = tb & 31;
        int kt = tt >> 2;                    // k-tile 0..7
        int ct = tt & 3;                     // c-tile 0..3
        int i = t >> 2;                      // k row within tile 0..63
        int qd = t & 3;
        const float* rp = src + (size_t)(kt * 64 + i) * HID + ct * 64 + qd * 16;
        #pragma unroll
        for (int v = 0; v < 4; v++) {
            float4 x = *(const float4*)(rp + v * 4);
            T[qd * 16 + v * 4 + 0][i] = f2bf(x.x);
            T[qd * 16 + v * 4 + 1][i] = f2bf(x.y);
            T[qd * 16 + v * 4 + 2][i] = f2bf(x.z);
            T[qd * 16 + v * 4 + 3][i] = f2bf(x.w);
        }
        __syncthreads();
        int j = t >> 2;                      // c within 64-col tile
        int part = t & 3;
        uint4 o0 = *(const uint4*)&T[j][part * 16];      // k = kt*64+part*16 .. +7
        uint4 o1 = *(const uint4*)&T[j][part * 16 + 8];  // k = +8 .. +15
        int col = cofs + ct * 64 + j;
        int k0 = kt * 64 + part * 16;
        int it0 = k0 >> 5;
        int qg0 = (k0 & 31) >> 3;            // in {0,2}
        int c64 = col >> 6, nt = (col >> 4) & 3, rr = col & 15;
        char* base = (char*)wbT + (size_t)(it0 * 8 + c64) * 4096 + nt * 1024 + rr * 16;
        *(uint4*)(base + qg0 * 256) = o0;
        *(uint4*)(base + (qg0 + 1) * 256) = o1;
    }
}

// ---------------- k_l2: prototypes (mean commutes with layer2) + norms ----------------
__global__ __launch_bounds__(256) void k_l2(const float* __restrict__ ws_h1,
                                            const float* __restrict__ W2, const float* __restrict__ b2,
                                            float* __restrict__ ws_proto, float* __restrict__ ws_pn) {
    __shared__ float s_m[DIM];
    __shared__ float red[256];
    int w = blockIdx.x, t = threadIdx.x;
    for (int k = t; k < DIM; k += 256) {
        float m = 0.0f;
        #pragma unroll
        for (int s = 0; s < 5; s++) m += ws_h1[(w * 5 + s) * DIM + k];
        s_m[k] = m * 0.2f;
    }
    __syncthreads();
    float a0 = 0.0f, a1 = 0.0f;
    int c0 = t, c1 = t + 256;
    #pragma unroll 8
    for (int k = 0; k < DIM; k++) {
        float mk = s_m[k];
        a0 += W2[k * DIM + c0] * mk;
        a1 += W2[k * DIM + c1] * mk;
    }
    float v0 = a0 + b2[c0], v1 = a1 + b2[c1];
    ws_proto[w * DIM + c0] = v0;
    ws_proto[w * DIM + c1] = v1;
    red[t] = v0 * v0 + v1 * v1;
    __syncthreads();
    for (int s2 = 128; s2 > 0; s2 >>= 1) {
        if (t < s2) red[t] += red[t + s2];
        __syncthreads();
    }
    if (t == 0) ws_pn[w] = sqrtf(red[0]);
}

// ---------------- k_cd: distances (pure f32) + argmin + out_proto + qf -> frag-ordered qb ------
__global__ __launch_bounds__(256) void k_cd(const float* __restrict__ qf,
                                            const float* __restrict__ ws_proto, const float* __restrict__ ws_pn,
                                            const float* __restrict__ temp_p,
                                            float* __restrict__ out_dist, float* __restrict__ out_class,
                                            float* __restrict__ out_proto,
                                            unsigned short* __restrict__ qb, int do_qb) {
    __shared__ float dl[32][5];
    __shared__ float cl[32];
    int bx = blockIdx.x, t = threadIdx.x;
    int wv = t >> 6, lane = t & 63;

    if (bx < NWAY * NKPTS && t < 128) {
        f32x4 v = *(const f32x4*)(ws_proto + (bx / NKPTS) * DIM + t * 4);
        *(f32x4*)(out_proto + (size_t)bx * DIM + t * 4) = v;
    }

    float p[NWAY][8];
    #pragma unroll
    for (int w = 0; w < NWAY; w++) {
        f32x4 u0 = *(const f32x4*)(ws_proto + w * DIM + lane * 8);
        f32x4 u1 = *(const f32x4*)(ws_proto + w * DIM + lane * 8 + 4);
        p[w][0] = u0[0]; p[w][1] = u0[1]; p[w][2] = u0[2]; p[w][3] = u0[3];
        p[w][4] = u1[0]; p[w][5] = u1[1]; p[w][6] = u1[2]; p[w][7] = u1[3];
    }
    float pn[NWAY];
    #pragma unroll
    for (int w = 0; w < NWAY; w++) pn[w] = ws_pn[w];
    float invt = 1.0f / temp_p[0];

    int itc = lane >> 2, qgc = lane & 3;   // this lane's qb chunk coords (k = lane*8..+7)
    #pragma unroll
    for (int i = 0; i < 8; i++) {
        int rloc = wv * 8 + i;
        size_t rq = (size_t)bx * 32 + rloc;
        const float4* qp = (const float4*)(qf + rq * DIM + lane * 8);
        float4 a = qp[0], b = qp[1];
        float qv[8] = {a.x, a.y, a.z, a.w, b.x, b.y, b.z, b.w};
        if (do_qb) {
            unsigned int p0 = f2bf(qv[0]) | ((unsigned int)f2bf(qv[1]) << 16);
            unsigned int p1 = f2bf(qv[2]) | ((unsigned int)f2bf(qv[3]) << 16);
            unsigned int p2 = f2bf(qv[4]) | ((unsigned int)f2bf(qv[5]) << 16);
            unsigned int p3 = f2bf(qv[6]) | ((unsigned int)f2bf(qv[7]) << 16);
            int row = (int)(rq & 63);
            size_t mb2 = rq >> 6;
            int mt = row >> 4, rr = row & 15;
            char* dst = (char*)qb + mb2 * 65536 + (size_t)(itc * 4 + mt) * 1024 + (qgc * 16 + rr) * 16;
            *(uint4*)dst = make_uint4(p0, p1, p2, p3);
        }
        float s[6] = {0, 0, 0, 0, 0, 0};
        #pragma unroll
        for (int j = 0; j < 8; j++) {
            float v = qv[j];
            s[5] += v * v;
            #pragma unroll
            for (int w = 0; w < NWAY; w++) s[w] += v * p[w][j];
        }
        #pragma unroll
        for (int off = 32; off > 0; off >>= 1)
            #pragma unroll
            for (int k = 0; k < 6; k++) s[k] += __shfl_xor(s[k], off, 64);
        if (lane == 0) {
            float qn = sqrtf(s[5]);
            float mv = 1e30f;
            int ami = 0;
            #pragma unroll
            for (int w = 0; w < NWAY; w++) {
                float den = fmaxf(qn * pn[w], 1e-8f);
                float d = (1.0f - s[w] / den) * invt;
                dl[rloc][w] = d;
                if (d < mv) { mv = d; ami = w; }
            }
            cl[rloc] = (float)ami;
        }
    }
    __syncthreads();
    for (int i = t; i < 32 * NWAY * NKPTS; i += 256) {
        int q = i / (NWAY * NKPTS);
        int rem = i - q * (NWAY * NKPTS);
        out_dist[(size_t)bx * 32 * (NWAY * NKPTS) + i] = dl[q][rem / NKPTS];
    }
    if (t < 32) out_class[(size_t)bx * 32 + t] = cl[t];
}

// ---------------- shared epilogue: h=relu(C+b1) -> LDS f16 -> head2 + sigmoid ----------------
static __device__ __forceinline__ void epilogue(f32x4 acc[4][4], char* smem, int mb, int nb,
                                                int t, int wv, int lane, int r,
                                                const float* __restrict__ bo1, const float* __restrict__ Wo2,
                                                const float* __restrict__ bo2,
                                                const float* __restrict__ bc1, const float* __restrict__ Wc2,
                                                const float* __restrict__ bc2,
                                                const float* __restrict__ ic,
                                                float* __restrict__ out_kp, float* __restrict__ out_conf) {
    _Float16* hlds = (_Float16*)smem;              // 64 x stride 264 f16
    float* offlds = (float*)(smem + 33792);        // 128 f32
    const float* bias = nb ? bc1 : bo1;
    #pragma unroll
    for (int nt = 0; nt < 4; nt++) {
        int cl = wv * 64 + nt * 16 + r;
        float bv = bias[cl];
        #pragma unroll
        for (int mt = 0; mt < 4; mt++)
            #pragma unroll
            for (int rg = 0; rg < 4; rg++) {
                int ml = mt * 16 + (lane >> 4) * 4 + rg;
                float v = acc[mt][nt][rg] + bv;
                hlds[ml * 264 + cl] = (_Float16)fmaxf(v, 0.0f);
            }
    }
    __syncthreads();
    if (nb == 0) {
        if (t < 64) {
            float ox = bo2[0], oy = bo2[1];
            for (int c0 = 0; c0 < 256; c0 += 8) {
                half8 hv = *(const half8*)(hlds + t * 264 + c0);
                #pragma unroll
                for (int j = 0; j < 8; j++) {
                    float hf = (float)hv[j];
                    ox += hf * Wo2[(c0 + j) * 2];
                    oy += hf * Wo2[(c0 + j) * 2 + 1];
                }
            }
            offlds[t * 2] = ox;
            offlds[t * 2 + 1] = oy;
        }
        __syncthreads();
        for (int i = t; i < 64 * 34; i += 256) {
            int q = i / 34;
            int rem = i - q * 34;
            int j = rem & 1;
            size_t Q = (size_t)mb * 64 + q;
            float o = offlds[q * 2 + j];
            float sg = 1.0f / (1.0f + __expf(-o));
            out_kp[Q * 34 + rem] = sg * ic[Q * 2 + j];
        }
    } else {
        if (t < 64) {
            float cl2 = bc2[0];
            for (int c0 = 0; c0 < 256; c0 += 8) {
                half8 hv = *(const half8*)(hlds + t * 264 + c0);
                #pragma unroll
                for (int j = 0; j < 8; j++) cl2 += (float)hv[j] * Wc2[c0 + j];
            }
            offlds[t] = 1.0f / (1.0f + __expf(-cl2));
        }
        __syncthreads();
        for (int i = t; i < 64 * 17; i += 256) {
            int q = i / 17;
            out_conf[(size_t)mb * 64 * 17 + i] = offlds[q];
        }
    }
}

// ---------------- k_gr: register-direct MFMA GEMM — no LDS/barriers in the K-loop ------------
// A and B frags load straight global->VGPR (frag-ordered layouts); latency hidden by TLP +
// 1-iter register prefetch. B (512KB) is L2-resident; A (67MB bf16) streams once.
__global__ __launch_bounds__(256) void k_gr(const unsigned short* __restrict__ qb,
                                            const unsigned short* __restrict__ wbT,
                                            const float* __restrict__ bo1, const float* __restrict__ Wo2,
                                            const float* __restrict__ bo2,
                                            const float* __restrict__ bc1, const float* __restrict__ Wc2,
                                            const float* __restrict__ bc2,
                                            const float* __restrict__ ic,
                                            float* __restrict__ out_kp, float* __restrict__ out_conf) {
    __shared__ __align__(16) char smem[34816];
    int mb = blockIdx.x >> 1;
    int nb = blockIdx.x & 1;
    int t = threadIdx.x;
    int wv = t >> 6;
    int lane = t & 63;
    int r = lane & 15;

    f32x4 acc[4][4];
    #pragma unroll
    for (int i = 0; i < 4; i++)
        #pragma unroll
        for (int j = 0; j < 4; j++) { f32x4 z = {0.f, 0.f, 0.f, 0.f}; acc[i][j] = z; }

    const char* aP = (const char*)qb + (size_t)mb * 65536 + lane * 16;
    const char* bP = (const char*)wbT + (size_t)(nb * 4 + wv) * 4096 + lane * 16;

    bf16x8 a0[4], b0[4], a1[4], b1[4];
    #pragma unroll
    for (int mt = 0; mt < 4; mt++) a0[mt] = *(const bf16x8*)(aP + mt * 1024);
    #pragma unroll
    for (int nt = 0; nt < 4; nt++) b0[nt] = *(const bf16x8*)(bP + nt * 1024);

    for (int it = 0; it < 16; it += 2) {
        // prefetch it+1
        #pragma unroll
        for (int mt = 0; mt < 4; mt++) a1[mt] = *(const bf16x8*)(aP + (size_t)((it + 1) * 4 + mt) * 1024);
        #pragma unroll
        for (int nt = 0; nt < 4; nt++) b1[nt] = *(const bf16x8*)(bP + (size_t)(it + 1) * 32768 + nt * 1024);
        #pragma unroll
        for (int mt = 0; mt < 4; mt++)
            #pragma unroll
            for (int nt = 0; nt < 4; nt++)
                acc[mt][nt] = __builtin_amdgcn_mfma_f32_16x16x32_bf16(a0[mt], b0[nt], acc[mt][nt], 0, 0, 0);
        // prefetch it+2
        if (it + 2 < 16) {
            #pragma unroll
            for (int mt = 0; mt < 4; mt++) a0[mt] = *(const bf16x8*)(aP + (size_t)((it + 2) * 4 + mt) * 1024);
            #pragma unroll
            for (int nt = 0; nt < 4; nt++) b0[nt] = *(const bf16x8*)(bP + (size_t)(it + 2) * 32768 + nt * 1024);
        }
        #pragma unroll
        for (int mt = 0; mt < 4; mt++)
            #pragma unroll
            for (int nt = 0; nt < 4; nt++)
                acc[mt][nt] = __builtin_amdgcn_mfma_f32_16x16x32_bf16(a1[mt], b1[nt], acc[mt][nt], 0, 0, 0);
    }
    __syncthreads();
    epilogue(acc, smem, mb, nb, t, wv, lane, r, bo1, Wo2, bo2, bc1, Wc2, bc2, ic, out_kp, out_conf);
}

// ---------------- k_gs: fallback (no qb workspace): A frags packed from f32 qf -----------------
__global__ __launch_bounds__(256) void k_gs(const float* __restrict__ qf,
                                            const unsigned short* __restrict__ wbT,
                                            const float* __restrict__ bo1, const float* __restrict__ Wo2,
                                            const float* __restrict__ bo2,
                                            const float* __restrict__ bc1, const float* __restrict__ Wc2,
                                            const float* __restrict__ bc2,
                                            const float* __restrict__ ic,
                                            float* __restrict__ out_kp, float* __restrict__ out_conf) {
    __shared__ __align__(16) char smem[34816];
    int mb = blockIdx.x >> 1;
    int nb = blockIdx.x & 1;
    int t = threadIdx.x;
    int wv = t >> 6;
    int lane = t & 63;
    int r = lane & 15;
    int qg = lane >> 4;

    f32x4 acc[4][4];
    #pragma unroll
    for (int i = 0; i < 4; i++)
        #pragma unroll
        for (int j = 0; j < 4; j++) { f32x4 z = {0.f, 0.f, 0.f, 0.f}; acc[i][j] = z; }

    const char* bP = (const char*)wbT + (size_t)(nb * 4 + wv) * 4096 + lane * 16;

    for (int it = 0; it < 16; it++) {
        bf16x8 af[4], bf[4];
        #pragma unroll
        for (int mt = 0; mt < 4; mt++) {
            const float* ap = qf + (size_t)(mb * 64 + mt * 16 + r) * DIM + it * 32 + qg * 8;
            float4 x0 = *(const float4*)ap;
            float4 x1 = *(const float4*)(ap + 4);
            bf16x8 v;
            v[0] = (short)f2bf(x0.x); v[1] = (short)f2bf(x0.y);
            v[2] = (short)f2bf(x0.z); v[3] = (short)f2bf(x0.w);
            v[4] = (short)f2bf(x1.x); v[5] = (short)f2bf(x1.y);
            v[6] = (short)f2bf(x1.z); v[7] = (short)f2bf(x1.w);
            af[mt] = v;
        }
        #pragma unroll
        for (int nt = 0; nt < 4; nt++)
            bf[nt] = *(const bf16x8*)(bP + (size_t)it * 32768 + nt * 1024);
        #pragma unroll
        for (int mt = 0; mt < 4; mt++)
            #pragma unroll
            for (int nt = 0; nt < 4; nt++)
                acc[mt][nt] = __builtin_amdgcn_mfma_f32_16x16x32_bf16(af[mt], bf[nt], acc[mt][nt], 0, 0, 0);
    }
    __syncthreads();
    epilogue(acc, smem, mb, nb, t, wv, lane, r, bo1, Wo2, bo2, bc1, Wc2, bc2, ic, out_kp, out_conf);
}

extern "C" void kernel_launch(void* const* d_in, const int* in_sizes, int n_in,
                              void* d_out, int out_size, void* d_ws, size_t ws_size,
                              hipStream_t stream) {
    const float* sf = (const float*)d_in[0];
    const float* qf = (const float*)d_in[2];
    const float* ic = (const float*)d_in[3];
    const float* W1 = (const float*)d_in[4];
    const float* b1 = (const float*)d_in[5];
    const float* W2 = (const float*)d_in[6];
    const float* b2 = (const float*)d_in[7];
    const float* Wo1 = (const float*)d_in[8];
    const float* bo1 = (const float*)d_in[9];
    const float* Wo2 = (const float*)d_in[10];
    const float* bo2 = (const float*)d_in[11];
    const float* Wc1 = (const float*)d_in[12];
    const float* bc1 = (const float*)d_in[13];
    const float* Wc2 = (const float*)d_in[14];
    const float* bc2 = (const float*)d_in[15];
    const float* temp = (const float*)d_in[16];

    float* out = (float*)d_out;
    float* out_kp = out;                   // 65536*17*2
    float* out_conf = out + 2228224;       // 65536*17
    float* out_dist = out + 3342336;       // 65536*5*17
    float* out_class = out + 8912896;      // 65536
    float* out_proto = out + 8978432;      // 5*17*512

    char* ws = (char*)d_ws;
    float* ws_h1 = (float*)ws;                              // 25*512 f32
    float* ws_proto = (float*)(ws + 51200);                 // 5*512 f32
    float* ws_pn = (float*)(ws + 61440);                    // 5 f32
    unsigned short* ws_wbT = (unsigned short*)(ws + 65536); // 512KB frag-ordered [Wo1|Wc1]
    unsigned short* ws_qb = (unsigned short*)(ws + 1048576); // 67MB frag-ordered bf16 qf
    int use_qb = (ws_size >= (size_t)1048576 + 67108864) ? 1 : 0;

    hipLaunchKernelGGL(k_l1, dim3(114), dim3(256), 0, stream, sf, W1, b1, Wo1, Wc1, ws_h1, ws_wbT);
    hipLaunchKernelGGL(k_l2, dim3(5), dim3(256), 0, stream, ws_h1, W2, b2, ws_proto, ws_pn);
    hipLaunchKernelGGL(k_cd, dim3(2048), dim3(256), 0, stream, qf, ws_proto, ws_pn, temp,
                       out_dist, out_class, out_proto, ws_qb, use_qb);
    if (use_qb) {
        hipLaunchKernelGGL(k_gr, dim3(2048), dim3(256), 0, stream, ws_qb, ws_wbT,
                           bo1, Wo2, bo2, bc1, Wc2, bc2, ic, out_kp, out_conf);
    } else {
        hipLaunchKernelGGL(k_gs, dim3(2048), dim3(256), 0, stream, qf, ws_wbT,
                           bo1, Wo2, bo2, bc1, Wc2, bc2, ic, out_kp, out_conf);
    }
}